// Round 1
// baseline (422.091 us; speedup 1.0000x reference)
//
#include <hip/hip_runtime.h>

// BlurPool3D: depthwise 3D conv, filt = ([1,2,1]^3)/64, stride 2, zero-pad 1.
// Input  (N=2, C=64, D=64, H=96, W=96) fp32
// Output (N=2, C=64, OD=32, OH=48, OW=48) fp32
//
// R2: LDS-staged version. Each block stages the contiguous [nr x 96] row-slab
// of one input plane via lane-linear float4 loads (memcpy pattern -> full
// per-instruction coalescing), double-buffered in LDS (pitch 97 to break
// power-of-2 bank aliasing), 1-plane register prefetch, ONE __syncthreads per
// plane. Stencil computed from LDS; rolling-z register carries the 2D-conv of
// the odd plane (a = c). Each input row is fetched from HBM exactly once per
// block (vs ~1.5x before), and staging loads are independent -> high MLP.

namespace {
constexpr int D = 64, H = 96, W = 96;
constexpr int OD = 32, OH = 48, OW = 48;
constexpr int HW = H * W;          // 9216
constexpr int YB = 16;             // output rows per block
constexpr int ZCH = 8;             // z outputs per chunk
constexpr int NT  = 192;           // threads per block (12 x 16) = 3 waves
constexpr int RP  = 97;            // LDS row pitch (floats); 96+1 pad
constexpr int MAXR = 33;           // staged rows per plane-slab
constexpr int WF4 = W / 4;         // 24 float4 per row
}

typedef float f4 __attribute__((ext_vector_type(4)));

__global__ __launch_bounds__(NT) void blurpool3d_kernel(
    const float* __restrict__ in, float* __restrict__ out)
{
    __shared__ float lds[2][MAXR * RP];   // 2 x 12.8 KB -> 6 blocks/CU fit

    const int xg  = threadIdx.x;          // 0..11 (4 outputs each)
    const int yl  = threadIdx.y;          // 0..15
    const int tid = yl * 12 + xg;
    const int y   = blockIdx.x * YB + yl; // 0..47
    const int z0  = blockIdx.y * ZCH;     // 0,8,16,24
    const long nc = blockIdx.z;           // 0..127

    const float* __restrict__ inp = in + nc * (long)(D * HW);
    float* __restrict__ outp = out + nc * (long)(OD * OH * OW)
                                   + (long)y * OW + xg * 4;

    // Row-slab this y-chunk needs: rows [2*y0-1 .. 2*y0+31] clamped to [0,95].
    const int s0  = (blockIdx.x == 0) ? 0 : (2 * blockIdx.x * YB - 1); // 0,31,63
    const int nr  = (blockIdx.x == 0) ? 32 : 33;
    const int nf4 = nr * WF4;             // 768 or 792 float4 per slab

    // Plane sequence: [2*z0-1, 2*z0 .. 2*z0+15] (17) or [0..15] when z0==0.
    const int kFirst = (z0 > 0) ? (2 * z0 - 1) : 0;
    const int nPl    = (z0 > 0) ? (2 * ZCH + 1) : (2 * ZCH);
    const float* srcBase = inp + (long)kFirst * HW + s0 * W;

    // y-conv rows (LDS-relative); top zero-pad handled by w0=0 on clamped row.
    const int   yb = 2 * y - 1;
    const int   r0 = (yb > 0 ? yb : 0) - s0;
    const int   r1 = yb + 1 - s0;
    const int   r2 = yb + 2 - s0;
    const float w0 = (y > 0) ? 1.0f : 0.0f;
    const int   xb = xg * 8;
    const bool  hasL = (xg > 0);

    // b_j = h[2j] + 2*h[2j+1] + h[2j+2], h[k] = slabrow[xb-1+k]
    auto rowconvL = [&](const float* base, int row) -> f4 {
        const float* r = base + row * RP + xb;
        float h0 = hasL ? r[-1] : 0.0f;   // x zero-pad at col -1
        float a0 = r[0], a1 = r[1], a2 = r[2], a3 = r[3];
        float a4 = r[4], a5 = r[5], a6 = r[6], a7 = r[7];
        f4 b;
        b.x = h0 + 2.0f * a0 + a1;
        b.y = a1 + 2.0f * a2 + a3;
        b.z = a3 + 2.0f * a4 + a5;
        b.w = a5 + 2.0f * a6 + a7;
        return b;
    };

    auto planeconvL = [&](const float* base) -> f4 {
        f4 ra = rowconvL(base, r0);
        f4 rb = rowconvL(base, r1);
        f4 rc = rowconvL(base, r2);
        return w0 * ra + 2.0f * rb + rc;
    };

    // Lane-linear contiguous staging: f4 index i covers slab float [4i..4i+3];
    // global side is one contiguous nr*96-float region -> perfect coalescing.
    auto stageLoad = [&](int pk, f4* regs) {
        const float* src = srcBase + (long)pk * HW;
        #pragma unroll
        for (int j = 0; j < 5; ++j) {
            const int i = tid + j * NT;
            if (i < nf4) regs[j] = *(const f4*)(src + 4 * i);
        }
    };
    auto stageWrite = [&](float* dst, const f4* regs) {
        #pragma unroll
        for (int j = 0; j < 5; ++j) {
            const int i = tid + j * NT;
            if (i < nf4) {
                const int row = i / WF4;          // magic-mul
                const int q   = i - row * WF4;
                float* p = dst + row * RP + 4 * q;
                p[0] = regs[j].x; p[1] = regs[j].y;
                p[2] = regs[j].z; p[3] = regs[j].w;
            }
        }
    };

    // Prologue: stage first plane into buffer 0.
    f4 regs[5];
    stageLoad(0, regs);
    stageWrite(&lds[0][0], regs);
    __syncthreads();

    f4 a = {0.0f, 0.0f, 0.0f, 0.0f};      // z zero-pad: plane -1 contributes 0
    f4 b = a;
    int buf = 0;
    const int tOff = (z0 > 0) ? 1 : 0;

    for (int k = 0; k < nPl; ++k) {
        const bool more = (k + 1 < nPl);
        if (more) stageLoad(k + 1, regs);  // issue next-plane loads FIRST

        const f4 v = planeconvL(&lds[buf][0]);   // compute hides load latency

        const int t = k - tOff;            // -1: a-init; even: b; odd: c+emit
        if (t < 0) {
            a = v;
        } else if ((t & 1) == 0) {
            b = v;
        } else {
            f4 o = (a + 2.0f * b + v) * 0.015625f;
            *(f4*)(outp + (long)(z0 + (t >> 1)) * (OH * OW)) = o;
            a = v;                          // rolling register
        }

        if (more) stageWrite(&lds[buf ^ 1][0], regs);
        __syncthreads();                    // one barrier per plane
        buf ^= 1;
    }
}

extern "C" void kernel_launch(void* const* d_in, const int* in_sizes, int n_in,
                              void* d_out, int out_size, void* d_ws, size_t ws_size,
                              hipStream_t stream)
{
    const float* x = (const float*)d_in[0];
    float* outp = (float*)d_out;
    dim3 grid(OH / YB, OD / ZCH, 128);     // (3, 4, 128) = 1536 blocks
    dim3 block(12, YB);                    // 192 threads = 3 waves
    blurpool3d_kernel<<<grid, block, 0, stream>>>(x, outp);
}

// Round 2
// 413.000 us; speedup vs baseline: 1.0220x; 1.0220x over previous
//
#include <hip/hip_runtime.h>

// BlurPool3D: depthwise 3D conv, filt = ([1,2,1]^3)/64, stride 2, zero-pad 1.
// Input  (N=2, C=64, D=64, H=96, W=96) fp32
// Output (N=2, C=64, OD=32, OH=48, OW=48) fp32
//
// R3: revert to the R1 register-rolling structure (kernel ~43 us, effective
// ~7.9 TB/s incl. L3 hits -- at/above the HBM roofline for the compulsory
// 340 MB of traffic). The R2 LDS-staged variant measured +13 us: barrier +
// LDS round-trip overhead on an already memory-roofline kernel.
// Single change vs R1: non-temporal output stores (output is never re-read;
// keeps input lines resident in L2/L3 for the z-chunk halo re-reads).
//
// 4 x-outputs per thread via two aligned float4 loads (+1 predicated scalar
// for the left halo), rolling-z register over chunks of 8 output z.
// Block (12,16)=192 threads; grid (3 y-chunks, 4 z-chunks, 128 nc).

namespace {
constexpr int D = 64, H = 96, W = 96;
constexpr int OD = 32, OH = 48, OW = 48;
constexpr int HW = H * W;        // 9216
constexpr int YB = 16;           // y rows per block
constexpr int ZCH = 8;           // z outputs per chunk
}

typedef float f4 __attribute__((ext_vector_type(4)));

__global__ __launch_bounds__(192) void blurpool3d_kernel(
    const float* __restrict__ in, float* __restrict__ out)
{
    const int xg = threadIdx.x;              // 0..11  (4 outputs each)
    const int yl = threadIdx.y;              // 0..15
    const int y  = blockIdx.x * YB + yl;     // 0..47
    const int z0 = blockIdx.y * ZCH;         // 0,8,16,24
    const long nc = blockIdx.z;              // 0..127

    const float* __restrict__ inp = in + nc * (long)(D * HW);
    float* __restrict__ outp = out + nc * (long)(OD * OH * OW)
                                   + (long)y * OW + xg * 4;

    const int xb = xg * 8;                   // cols xb..xb+7 -> h[1..8]; h[0]=col xb-1
    const int yb = 2 * y - 1;
    const int r0i = (y > 0) ? yb : 0;        // clamped (weight 0 when y==0)
    const float w0 = (y > 0) ? 1.0f : 0.0f;
    const int r1i = yb + 1, r2i = yb + 2;    // always in [0,95]
    const bool has_left = (xg > 0);

    // b_j = h[2j] + 2*h[2j+1] + h[2j+2], h[k] = plane[row][xb-1+k]
    auto rowconv = [&](const float* plane, int row) -> f4 {
        const float* r = plane + row * W + xb;
        f4 A = *(const f4*)(r);              // cols xb..xb+3   (16B aligned)
        f4 B = *(const f4*)(r + 4);          // cols xb+4..xb+7 (16B aligned)
        float h0 = has_left ? r[-1] : 0.0f;
        f4 b;
        b.x = h0  + 2.0f * A.x + A.y;
        b.y = A.y + 2.0f * A.z + A.w;
        b.z = A.w + 2.0f * B.x + B.y;
        b.w = B.y + 2.0f * B.z + B.w;
        return b;
    };

    auto planeconv = [&](const float* plane) -> f4 {
        f4 ra = rowconv(plane, r0i);
        f4 rb = rowconv(plane, r1i);
        f4 rc = rowconv(plane, r2i);
        return w0 * ra + 2.0f * rb + rc;
    };

    // Rolling register: 2D conv of input plane (2z-1); plane -1 is zero pad.
    f4 a = {0.0f, 0.0f, 0.0f, 0.0f};
    if (z0 != 0) a = planeconv(inp + (2 * z0 - 1) * HW);

    for (int zi = 0; zi < ZCH; ++zi) {
        const int z = z0 + zi;
        f4 b = planeconv(inp + (2 * z) * HW);
        f4 c = planeconv(inp + (2 * z + 1) * HW);
        f4 o = (a + 2.0f * b + c) * 0.015625f;
        __builtin_nontemporal_store(o, (f4*)(outp + (long)z * (OH * OW)));
        a = c;
    }
}

extern "C" void kernel_launch(void* const* d_in, const int* in_sizes, int n_in,
                              void* d_out, int out_size, void* d_ws, size_t ws_size,
                              hipStream_t stream)
{
    const float* x = (const float*)d_in[0];
    float* outp = (float*)d_out;
    dim3 grid(OH / YB, OD / ZCH, 128);       // (3, 4, 128)
    dim3 block(12, YB);                      // 192 threads = 3 waves
    blurpool3d_kernel<<<grid, block, 0, stream>>>(x, outp);
}